// Round 5
// baseline (13391.275 us; speedup 1.0000x reference)
//
#include <hip/hip_runtime.h>

// Fused persistent DOPRI5 — round-4 mechanics (proven correct), de-spilled.
// 8 waves/block x 16 rows/wave, grid 256 = 1 block/CU, 2 waves/SIMD.
// State: y fp32 + k1 fp32 + k2..k5 as packed-bf16 DELTAS vs k1 (~205 VGPRs,
// under the 256 arch-VGPR cap -> no scratch). W1^T and W2^T staged in LDS
// bf16 (stride 136); B-fragments read per use (b128). C/D->A transpose via
// per-wave row-major LDS bounce: scalar b16 writes + b128 reads — plain C++
// only, compiler tracks all LDS dependencies. No inline asm anywhere.
// launch_bounds(512,1): 1 block/CU under CUDA semantics (observed r4:
// arg2=2 -> VGPR cap 128 = blocks/CU interpretation), cap 256 either way.

#define DT 0.01f
#define N_STEPS 100
#define W1S 136  // ushorts per n-row (272 B, 16B-aligned)

typedef __attribute__((ext_vector_type(8))) short short8;
typedef __attribute__((ext_vector_type(4))) float f32x4;

// DT-premultiplied DOPRI5 tableau
#define A21 (DT * 0.2f)
#define A31 (DT * 3.0f / 40.0f)
#define A32 (DT * 9.0f / 40.0f)
#define A41 (DT * 44.0f / 45.0f)
#define A42 (-DT * 56.0f / 15.0f)
#define A43 (DT * 32.0f / 9.0f)
#define A51 (DT * 19372.0f / 6561.0f)
#define A52 (-DT * 25360.0f / 2187.0f)
#define A53 (DT * 64448.0f / 6561.0f)
#define A54 (-DT * 212.0f / 729.0f)
#define A61 (DT * 9017.0f / 3168.0f)
#define A62 (-DT * 355.0f / 33.0f)
#define A63 (DT * 46732.0f / 5247.0f)
#define A64 (DT * 49.0f / 176.0f)
#define A65 (-DT * 5103.0f / 18656.0f)
#define B1 (DT * 35.0f / 384.0f)
#define B3 (DT * 500.0f / 1113.0f)
#define B4 (DT * 125.0f / 192.0f)
#define B5 (-DT * 2187.0f / 6784.0f)
#define B6 (DT * 11.0f / 84.0f)

// delta form: z_i = y + (sum_j a_ij)*k1 + sum_{j>=2} a_ij*(k_j - k1)
#define C2_1 (A21)
#define C3_1 (A31 + A32)
#define C4_1 (A41 + A42 + A43)
#define C5_1 (A51 + A52 + A53 + A54)
#define C6_1 (A61 + A62 + A63 + A64 + A65)
#define CY_1 (B1 + B3 + B4 + B5)

__device__ __forceinline__ unsigned short f2bf(float f) {
  unsigned u = __builtin_bit_cast(unsigned, f);
  u += 0x7fffu + ((u >> 16) & 1u);  // round-to-nearest-even
  return (unsigned short)(u >> 16);
}

__device__ __forceinline__ float bflo(unsigned d) {
  return __builtin_bit_cast(float, d << 16);
}
__device__ __forceinline__ float bfhi(unsigned d) {
  return __builtin_bit_cast(float, d & 0xffff0000u);
}

__device__ __forceinline__ float fast_tanh(float x) {
  float xc = fminf(fmaxf(x, -9.f), 9.f);
  float e = __expf(2.f * xc);
  return 1.f - 2.f * __builtin_amdgcn_rcpf(e + 1.f);
}

// One f(z) evaluation for this wave's 16-row tile.
// zfun(slot)->float; kfun(nt, f32x4) consumes k=f(z) (bias2 included).
template <typename ZF, typename KF>
__device__ __forceinline__ void feval(unsigned short* zb,
                                      const unsigned short* w1t,
                                      const unsigned short* w2t,
                                      const float (&bias1)[8],
                                      const float (&bias2)[8], int kg, int ln,
                                      ZF zfun, KF kfun) {
  // ---- write z (bf16) to bounce buffer, row-major [16][136] ----
#pragma unroll
  for (int nt = 0; nt < 8; nt++)
#pragma unroll
    for (int r = 0; r < 4; r++)
      zb[(4 * kg + r) * W1S + nt * 16 + ln] = f2bf(zfun(nt * 4 + r));

  // ---- read A fragments: lane holds A[row=ln][k = ks*32 + kg*8 + j] ----
  short8 af[4];
#pragma unroll
  for (int ks = 0; ks < 4; ks++)
    af[ks] = *(const short8*)&zb[ln * W1S + ks * 32 + kg * 8];

  // ---- GEMM1 (B = W1 from LDS) + bias + tanh, write h back ----
#pragma unroll
  for (int nt = 0; nt < 8; nt++) {
    f32x4 acc = {bias1[nt], bias1[nt], bias1[nt], bias1[nt]};
#pragma unroll
    for (int ks = 0; ks < 4; ks++) {
      short8 bfrag = *(const short8*)&w1t[(nt * 16 + ln) * W1S + ks * 32 + kg * 8];
      acc = __builtin_amdgcn_mfma_f32_16x16x32_bf16(af[ks], bfrag, acc, 0, 0, 0);
    }
#pragma unroll
    for (int r = 0; r < 4; r++)
      zb[(4 * kg + r) * W1S + nt * 16 + ln] = f2bf(fast_tanh(acc[r]));
  }

  // ---- read h A-fragments ----
  short8 ah[4];
#pragma unroll
  for (int ks = 0; ks < 4; ks++)
    ah[ks] = *(const short8*)&zb[ln * W1S + ks * 32 + kg * 8];

  // ---- GEMM2 (B = W2 from LDS) + bias -> kfun ----
#pragma unroll
  for (int nt = 0; nt < 8; nt++) {
    f32x4 acc = {bias2[nt], bias2[nt], bias2[nt], bias2[nt]};
#pragma unroll
    for (int ks = 0; ks < 4; ks++) {
      short8 bfrag = *(const short8*)&w2t[(nt * 16 + ln) * W1S + ks * 32 + kg * 8];
      acc = __builtin_amdgcn_mfma_f32_16x16x32_bf16(ah[ks], bfrag, acc, 0, 0, 0);
    }
    kfun(nt, acc);
  }
}

__global__ __launch_bounds__(512, 1) void ode_kernel(
    const float* __restrict__ x, const float* __restrict__ W1,
    const float* __restrict__ b1, const float* __restrict__ W2,
    const float* __restrict__ b2, float* __restrict__ out) {
  __shared__ unsigned short w1t[128 * W1S];      // 34816 B: W1^T bf16 [n][k]
  __shared__ unsigned short w2t[128 * W1S];      // 34816 B: W2^T bf16 [n][k]
  __shared__ unsigned short zb_all[8][16 * W1S]; // 34816 B: per-wave bounce

  const int tid = threadIdx.x;
  const int wave = tid >> 6;
  const int lane = tid & 63;
  const int ln = lane & 15;   // MFMA col within tile / A row
  const int kg = lane >> 4;   // lane group

  // one-time: stage W1^T and W2^T into LDS as bf16
  for (int i = tid; i < 128 * 128; i += 512) {
    int k = i >> 7, n = i & 127;
    w1t[n * W1S + k] = f2bf(W1[i]);
    w2t[n * W1S + k] = f2bf(W2[i]);
  }
  __syncthreads();

  float bias1[8], bias2[8];
#pragma unroll
  for (int nt = 0; nt < 8; nt++) {
    bias1[nt] = b1[nt * 16 + ln];
    bias2[nt] = b2[nt * 16 + ln];
  }

  unsigned short* zb = &zb_all[wave][0];
  const int rowbase = blockIdx.x * 128 + wave * 16;

  // State in C/D layout: slot i = nt*4 + r holds element [row=4*kg+r][col=nt*16+ln]
  // y, k1 fp32; k2..k5 as packed-bf16 deltas vs k1: kd[i-2][slot>>1]
  float y[32], k1f[32];
  unsigned kd[4][16];
#pragma unroll
  for (int nt = 0; nt < 8; nt++)
#pragma unroll
    for (int r = 0; r < 4; r++)
      y[nt * 4 + r] = x[(rowbase + 4 * kg + r) * 128 + nt * 16 + ln];

  auto dv = [&](int i, int s) -> float {  // delta k_{i+2} - k1
    unsigned d = kd[i][s >> 1];
    return (s & 1) ? bfhi(d) : bflo(d);
  };
  auto dstore = [&](int i, int nt, f32x4 a) {
    unsigned lo0 = f2bf(a[0] - k1f[nt * 4 + 0]);
    unsigned hi0 = f2bf(a[1] - k1f[nt * 4 + 1]);
    unsigned lo1 = f2bf(a[2] - k1f[nt * 4 + 2]);
    unsigned hi1 = f2bf(a[3] - k1f[nt * 4 + 3]);
    kd[i][nt * 2 + 0] = lo0 | (hi0 << 16);
    kd[i][nt * 2 + 1] = lo1 | (hi1 << 16);
  };

#pragma unroll 1
  for (int step = 0; step < N_STEPS; step++) {
    feval(zb, w1t, w2t, bias1, bias2, kg, ln,
          [&](int s) { return y[s]; },
          [&](int nt, f32x4 a) {
#pragma unroll
            for (int r = 0; r < 4; r++) k1f[nt * 4 + r] = a[r];
          });
    feval(zb, w1t, w2t, bias1, bias2, kg, ln,
          [&](int s) { return __builtin_fmaf(C2_1, k1f[s], y[s]); },
          [&](int nt, f32x4 a) { dstore(0, nt, a); });
    feval(zb, w1t, w2t, bias1, bias2, kg, ln,
          [&](int s) {
            float z = __builtin_fmaf(C3_1, k1f[s], y[s]);
            return __builtin_fmaf(A32, dv(0, s), z);
          },
          [&](int nt, f32x4 a) { dstore(1, nt, a); });
    feval(zb, w1t, w2t, bias1, bias2, kg, ln,
          [&](int s) {
            float z = __builtin_fmaf(C4_1, k1f[s], y[s]);
            z = __builtin_fmaf(A42, dv(0, s), z);
            return __builtin_fmaf(A43, dv(1, s), z);
          },
          [&](int nt, f32x4 a) { dstore(2, nt, a); });
    feval(zb, w1t, w2t, bias1, bias2, kg, ln,
          [&](int s) {
            float z = __builtin_fmaf(C5_1, k1f[s], y[s]);
            z = __builtin_fmaf(A52, dv(0, s), z);
            z = __builtin_fmaf(A53, dv(1, s), z);
            return __builtin_fmaf(A54, dv(2, s), z);
          },
          [&](int nt, f32x4 a) { dstore(3, nt, a); });
    feval(zb, w1t, w2t, bias1, bias2, kg, ln,
          [&](int s) {
            float z = __builtin_fmaf(C6_1, k1f[s], y[s]);
            z = __builtin_fmaf(A62, dv(0, s), z);
            z = __builtin_fmaf(A63, dv(1, s), z);
            z = __builtin_fmaf(A64, dv(2, s), z);
            return __builtin_fmaf(A65, dv(3, s), z);
          },
          [&](int nt, f32x4 a) {
#pragma unroll
            for (int r = 0; r < 4; r++) {
              int s = nt * 4 + r;
              float inc = CY_1 * k1f[s];
              inc = __builtin_fmaf(B3, dv(1, s), inc);
              inc = __builtin_fmaf(B4, dv(2, s), inc);
              inc = __builtin_fmaf(B5, dv(3, s), inc);
              inc = __builtin_fmaf(B6, a[r], inc);
              y[s] += inc;
            }
          });
  }

#pragma unroll
  for (int nt = 0; nt < 8; nt++)
#pragma unroll
    for (int r = 0; r < 4; r++)
      out[(rowbase + 4 * kg + r) * 128 + nt * 16 + ln] = y[nt * 4 + r];
}

extern "C" void kernel_launch(void* const* d_in, const int* in_sizes, int n_in,
                              void* d_out, int out_size, void* d_ws,
                              size_t ws_size, hipStream_t stream) {
  const float* x = (const float*)d_in[0];
  const float* W1 = (const float*)d_in[1];
  const float* b1 = (const float*)d_in[2];
  const float* W2 = (const float*)d_in[3];
  const float* b2 = (const float*)d_in[4];
  float* out = (float*)d_out;

  dim3 grid(256), block(512);
  hipLaunchKernelGGL(ode_kernel, grid, block, 0, stream, x, W1, b1, W2, b2,
                     out);
}

// Round 6
// 5282.796 us; speedup vs baseline: 2.5349x; 2.5349x over previous
//
#include <hip/hip_runtime.h>

// Fused persistent DOPRI5 — round-5 numerics, 4-wave workgroups.
// Register model (fits r1/r4/r5 evidence): 8-wave WG -> >=2 waves/SIMD ->
// unified budget 256 -> compiler splits 128 arch VGPR + 128 AGPR -> spills.
// 4-wave WG (256 thr) -> 1 wave/SIMD -> 256 arch VGPRs. State fits in ~205.
// Each wave: 16 rows, all 100 steps. Grid 512 = 2 sequential passes over CUs.
// State: y fp32 + k1 fp32 + k2..k5 as packed-bf16 DELTAS vs k1. W1^T, W2^T in
// LDS bf16 (stride 136); C/D->A transpose via per-wave row-major LDS bounce:
// scalar b16 writes + b128 reads. Plain C++ only, no inline asm.

#define DT 0.01f
#define N_STEPS 100
#define W1S 136  // ushorts per n-row (272 B, 16B-aligned)

typedef __attribute__((ext_vector_type(8))) short short8;
typedef __attribute__((ext_vector_type(4))) float f32x4;

// DT-premultiplied DOPRI5 tableau
#define A21 (DT * 0.2f)
#define A31 (DT * 3.0f / 40.0f)
#define A32 (DT * 9.0f / 40.0f)
#define A41 (DT * 44.0f / 45.0f)
#define A42 (-DT * 56.0f / 15.0f)
#define A43 (DT * 32.0f / 9.0f)
#define A51 (DT * 19372.0f / 6561.0f)
#define A52 (-DT * 25360.0f / 2187.0f)
#define A53 (DT * 64448.0f / 6561.0f)
#define A54 (-DT * 212.0f / 729.0f)
#define A61 (DT * 9017.0f / 3168.0f)
#define A62 (-DT * 355.0f / 33.0f)
#define A63 (DT * 46732.0f / 5247.0f)
#define A64 (DT * 49.0f / 176.0f)
#define A65 (-DT * 5103.0f / 18656.0f)
#define B1 (DT * 35.0f / 384.0f)
#define B3 (DT * 500.0f / 1113.0f)
#define B4 (DT * 125.0f / 192.0f)
#define B5 (-DT * 2187.0f / 6784.0f)
#define B6 (DT * 11.0f / 84.0f)

// delta form: z_i = y + (sum_j a_ij)*k1 + sum_{j>=2} a_ij*(k_j - k1)
#define C2_1 (A21)
#define C3_1 (A31 + A32)
#define C4_1 (A41 + A42 + A43)
#define C5_1 (A51 + A52 + A53 + A54)
#define C6_1 (A61 + A62 + A63 + A64 + A65)
#define CY_1 (B1 + B3 + B4 + B5)

__device__ __forceinline__ unsigned short f2bf(float f) {
  unsigned u = __builtin_bit_cast(unsigned, f);
  u += 0x7fffu + ((u >> 16) & 1u);  // round-to-nearest-even
  return (unsigned short)(u >> 16);
}

__device__ __forceinline__ float bflo(unsigned d) {
  return __builtin_bit_cast(float, d << 16);
}
__device__ __forceinline__ float bfhi(unsigned d) {
  return __builtin_bit_cast(float, d & 0xffff0000u);
}

__device__ __forceinline__ float fast_tanh(float x) {
  float xc = fminf(fmaxf(x, -9.f), 9.f);
  float e = __expf(2.f * xc);
  return 1.f - 2.f * __builtin_amdgcn_rcpf(e + 1.f);
}

// One f(z) evaluation for this wave's 16-row tile.
// zfun(slot)->float; kfun(nt, f32x4) consumes k=f(z) (bias2 included).
template <typename ZF, typename KF>
__device__ __forceinline__ void feval(unsigned short* zb,
                                      const unsigned short* w1t,
                                      const unsigned short* w2t,
                                      const float (&bias1)[8],
                                      const float (&bias2)[8], int kg, int ln,
                                      ZF zfun, KF kfun) {
  // ---- write z (bf16) to bounce buffer, row-major [16][136] ----
#pragma unroll
  for (int nt = 0; nt < 8; nt++)
#pragma unroll
    for (int r = 0; r < 4; r++)
      zb[(4 * kg + r) * W1S + nt * 16 + ln] = f2bf(zfun(nt * 4 + r));

  // ---- read A fragments: lane holds A[row=ln][k = ks*32 + kg*8 + j] ----
  short8 af[4];
#pragma unroll
  for (int ks = 0; ks < 4; ks++)
    af[ks] = *(const short8*)&zb[ln * W1S + ks * 32 + kg * 8];

  // ---- GEMM1 (B = W1 from LDS) + bias + tanh, write h back ----
#pragma unroll
  for (int nt = 0; nt < 8; nt++) {
    f32x4 acc = {bias1[nt], bias1[nt], bias1[nt], bias1[nt]};
#pragma unroll
    for (int ks = 0; ks < 4; ks++) {
      short8 bfrag = *(const short8*)&w1t[(nt * 16 + ln) * W1S + ks * 32 + kg * 8];
      acc = __builtin_amdgcn_mfma_f32_16x16x32_bf16(af[ks], bfrag, acc, 0, 0, 0);
    }
#pragma unroll
    for (int r = 0; r < 4; r++)
      zb[(4 * kg + r) * W1S + nt * 16 + ln] = f2bf(fast_tanh(acc[r]));
  }

  // ---- read h A-fragments ----
  short8 ah[4];
#pragma unroll
  for (int ks = 0; ks < 4; ks++)
    ah[ks] = *(const short8*)&zb[ln * W1S + ks * 32 + kg * 8];

  // ---- GEMM2 (B = W2 from LDS) + bias -> kfun ----
#pragma unroll
  for (int nt = 0; nt < 8; nt++) {
    f32x4 acc = {bias2[nt], bias2[nt], bias2[nt], bias2[nt]};
#pragma unroll
    for (int ks = 0; ks < 4; ks++) {
      short8 bfrag = *(const short8*)&w2t[(nt * 16 + ln) * W1S + ks * 32 + kg * 8];
      acc = __builtin_amdgcn_mfma_f32_16x16x32_bf16(ah[ks], bfrag, acc, 0, 0, 0);
    }
    kfun(nt, acc);
  }
}

__global__ __launch_bounds__(256, 1) void ode_kernel(
    const float* __restrict__ x, const float* __restrict__ W1,
    const float* __restrict__ b1, const float* __restrict__ W2,
    const float* __restrict__ b2, float* __restrict__ out) {
  __shared__ unsigned short w1t[128 * W1S];      // 34816 B: W1^T bf16 [n][k]
  __shared__ unsigned short w2t[128 * W1S];      // 34816 B: W2^T bf16 [n][k]
  __shared__ unsigned short zb_all[4][16 * W1S]; // 17408 B: per-wave bounce

  const int tid = threadIdx.x;
  const int wave = tid >> 6;
  const int lane = tid & 63;
  const int ln = lane & 15;   // MFMA col within tile / A row
  const int kg = lane >> 4;   // lane group

  // one-time: stage W1^T and W2^T into LDS as bf16
  for (int i = tid; i < 128 * 128; i += 256) {
    int k = i >> 7, n = i & 127;
    w1t[n * W1S + k] = f2bf(W1[i]);
    w2t[n * W1S + k] = f2bf(W2[i]);
  }
  __syncthreads();

  float bias1[8], bias2[8];
#pragma unroll
  for (int nt = 0; nt < 8; nt++) {
    bias1[nt] = b1[nt * 16 + ln];
    bias2[nt] = b2[nt * 16 + ln];
  }

  unsigned short* zb = &zb_all[wave][0];
  const int rowbase = blockIdx.x * 64 + wave * 16;

  // State in C/D layout: slot i = nt*4 + r holds element [row=4*kg+r][col=nt*16+ln]
  // y, k1 fp32; k2..k5 as packed-bf16 deltas vs k1: kd[i-2][slot>>1]
  float y[32], k1f[32];
  unsigned kd[4][16];
#pragma unroll
  for (int nt = 0; nt < 8; nt++)
#pragma unroll
    for (int r = 0; r < 4; r++)
      y[nt * 4 + r] = x[(rowbase + 4 * kg + r) * 128 + nt * 16 + ln];

  auto dv = [&](int i, int s) -> float {  // delta k_{i+2} - k1
    unsigned d = kd[i][s >> 1];
    return (s & 1) ? bfhi(d) : bflo(d);
  };
  auto dstore = [&](int i, int nt, f32x4 a) {
    unsigned lo0 = f2bf(a[0] - k1f[nt * 4 + 0]);
    unsigned hi0 = f2bf(a[1] - k1f[nt * 4 + 1]);
    unsigned lo1 = f2bf(a[2] - k1f[nt * 4 + 2]);
    unsigned hi1 = f2bf(a[3] - k1f[nt * 4 + 3]);
    kd[i][nt * 2 + 0] = lo0 | (hi0 << 16);
    kd[i][nt * 2 + 1] = lo1 | (hi1 << 16);
  };

#pragma unroll 1
  for (int step = 0; step < N_STEPS; step++) {
    feval(zb, w1t, w2t, bias1, bias2, kg, ln,
          [&](int s) { return y[s]; },
          [&](int nt, f32x4 a) {
#pragma unroll
            for (int r = 0; r < 4; r++) k1f[nt * 4 + r] = a[r];
          });
    feval(zb, w1t, w2t, bias1, bias2, kg, ln,
          [&](int s) { return __builtin_fmaf(C2_1, k1f[s], y[s]); },
          [&](int nt, f32x4 a) { dstore(0, nt, a); });
    feval(zb, w1t, w2t, bias1, bias2, kg, ln,
          [&](int s) {
            float z = __builtin_fmaf(C3_1, k1f[s], y[s]);
            return __builtin_fmaf(A32, dv(0, s), z);
          },
          [&](int nt, f32x4 a) { dstore(1, nt, a); });
    feval(zb, w1t, w2t, bias1, bias2, kg, ln,
          [&](int s) {
            float z = __builtin_fmaf(C4_1, k1f[s], y[s]);
            z = __builtin_fmaf(A42, dv(0, s), z);
            return __builtin_fmaf(A43, dv(1, s), z);
          },
          [&](int nt, f32x4 a) { dstore(2, nt, a); });
    feval(zb, w1t, w2t, bias1, bias2, kg, ln,
          [&](int s) {
            float z = __builtin_fmaf(C5_1, k1f[s], y[s]);
            z = __builtin_fmaf(A52, dv(0, s), z);
            z = __builtin_fmaf(A53, dv(1, s), z);
            return __builtin_fmaf(A54, dv(2, s), z);
          },
          [&](int nt, f32x4 a) { dstore(3, nt, a); });
    feval(zb, w1t, w2t, bias1, bias2, kg, ln,
          [&](int s) {
            float z = __builtin_fmaf(C6_1, k1f[s], y[s]);
            z = __builtin_fmaf(A62, dv(0, s), z);
            z = __builtin_fmaf(A63, dv(1, s), z);
            z = __builtin_fmaf(A64, dv(2, s), z);
            return __builtin_fmaf(A65, dv(3, s), z);
          },
          [&](int nt, f32x4 a) {
#pragma unroll
            for (int r = 0; r < 4; r++) {
              int s = nt * 4 + r;
              float inc = CY_1 * k1f[s];
              inc = __builtin_fmaf(B3, dv(1, s), inc);
              inc = __builtin_fmaf(B4, dv(2, s), inc);
              inc = __builtin_fmaf(B5, dv(3, s), inc);
              inc = __builtin_fmaf(B6, a[r], inc);
              y[s] += inc;
            }
          });
  }

#pragma unroll
  for (int nt = 0; nt < 8; nt++)
#pragma unroll
    for (int r = 0; r < 4; r++)
      out[(rowbase + 4 * kg + r) * 128 + nt * 16 + ln] = y[nt * 4 + r];
}

extern "C" void kernel_launch(void* const* d_in, const int* in_sizes, int n_in,
                              void* d_out, int out_size, void* d_ws,
                              size_t ws_size, hipStream_t stream) {
  const float* x = (const float*)d_in[0];
  const float* W1 = (const float*)d_in[1];
  const float* b1 = (const float*)d_in[2];
  const float* W2 = (const float*)d_in[3];
  const float* b2 = (const float*)d_in[4];
  float* out = (float*)d_out;

  dim3 grid(512), block(256);
  hipLaunchKernelGGL(ode_kernel, grid, block, 0, stream, x, W1, b1, W2, b2,
                     out);
}